// Round 8
// baseline (1406.605 us; speedup 1.0000x reference)
//
#include <hip/hip_runtime.h>
#include <hip/hip_bf16.h>

// Problem constants
#define B_ 128
#define S_ 128
#define W_ 16
#define V_ 128
#define H_ 512
#define L_ 64

typedef _Float16 f16x8 __attribute__((ext_vector_type(8)));
typedef float f32x4 __attribute__((ext_vector_type(4)));

__device__ __forceinline__ float sigm(float v) { return 1.0f / (1.0f + __expf(-v)); }
__device__ __forceinline__ float tanhf_(float v) { return 1.0f - 2.0f / (1.0f + __expf(2.0f * v)); }

__device__ __forceinline__ unsigned short f16bits(_Float16 h) {
    return __builtin_bit_cast(unsigned short, h);
}

// ---------------------------------------------------------------------------
// Workspace layout (bytes):
//   hbuf  u32 packed(hi,lo) [par2][dir2][128][512] @ 0        (1048576)
//   slots u32 [16 chains][8 blocks][32 pad]        @ 1048576  (16384)  (unused)
//   flag  i32                                      @ 1064960  (64)
//   xhi   u16 [128][128][128]                      @ 1065024  (4194304)
//   xlo   u16 [128][128][128]                      @ 5259328  (4194304)
//   whalf f16 [1966080]                            @ 9453632  (3932160)
//         [whhf 786432 | whhb 786432 | wihf 196608 | wihb 196608]
//   smallF f32 [71745]                             @ 13385792 (287040)
//         [bihf 1536|bhhf 1536|bihb 1536|bhhb 1536|wlin 65536|blin 64|fg 1]
//   Ycat  f16 [128][128][1024]                     @ 13672832 (33554432)
//   wlinh f16 [64][1024]                           @ 47227264 (131072)
//   wlinl f16 [64][1024]                           @ 47358336 (131072) -> ends 47489408
// ---------------------------------------------------------------------------
#define OFF_SLOT  1048576
#define OFF_FLAG  1064960
#define OFF_XHI   1065024
#define OFF_XLO   5259328
#define OFF_WH    9453632
#define OFF_SMALL 13385792
#define OFF_YCAT  13672832
#define OFF_WLH   47227264
#define OFF_WLL   47358336

// Runtime input-dtype detection (insurance): low-16 exponent-field vote.
__global__ void detect_kernel(const unsigned* __restrict__ w, int* __restrict__ flag) {
    __shared__ int sv[256];
    int tid = threadIdx.x;
    unsigned word = w[tid];
    unsigned e = (word >> 7) & 0xFFu;
    sv[tid] = (e >= 64u && e <= 126u) ? 1 : 0;
    __syncthreads();
    for (int s = 128; s > 0; s >>= 1) {
        if (tid < s) sv[tid] += sv[tid + s];
        __syncthreads();
    }
    if (tid == 0) *flag = (sv[0] >= 160) ? 1 : 0;  // 1 = inputs are bf16
}

// Canonicalize the 4 big weight matrices into packed fp16 (RTN) in ws.
__global__ void prep_whalf(const void* __restrict__ whhf, const void* __restrict__ whhb,
                           const void* __restrict__ wihf, const void* __restrict__ wihb,
                           _Float16* __restrict__ dst, const int* __restrict__ flag) {
    int i = blockIdx.x * 256 + threadIdx.x;  // grid covers 1966080 exactly
    const void* src;
    int off;
    if (i < 786432)       { src = whhf; off = i; }
    else if (i < 1572864) { src = whhb; off = i - 786432; }
    else if (i < 1769472) { src = wihf; off = i - 1572864; }
    else                  { src = wihb; off = i - 1769472; }
    float v = (*flag) ? __bfloat162float(((const __hip_bfloat16*)src)[off])
                      : ((const float*)src)[off];
    dst[i] = (_Float16)v;
}

// Canonicalize biases + W_lin + b_lin + forget into fp32 in ws.
__global__ void prep_small(const void* __restrict__ bihf, const void* __restrict__ bhhf,
                           const void* __restrict__ bihb, const void* __restrict__ bhhb,
                           const void* __restrict__ wlin, const void* __restrict__ blin,
                           const void* __restrict__ fg,
                           float* __restrict__ dst, const int* __restrict__ flag) {
    int i = blockIdx.x * 256 + threadIdx.x;
    if (i >= 71745) return;
    const void* src;
    int off;
    if (i < 1536)       { src = bihf; off = i; }
    else if (i < 3072)  { src = bhhf; off = i - 1536; }
    else if (i < 4608)  { src = bihb; off = i - 3072; }
    else if (i < 6144)  { src = bhhb; off = i - 4608; }
    else if (i < 71680) { src = wlin; off = i - 6144; }
    else if (i < 71744) { src = blin; off = i - 71680; }
    else                { src = fg;   off = 0; }
    float v = (*flag) ? __bfloat162float(((const __hip_bfloat16*)src)[off])
                      : ((const float*)src)[off];
    dst[i] = v;
}

// W_lin -> hi/lo f16 planes (hi + lo reproduces fp32 to ~2^-22).
__global__ void prep_wlin(const void* __restrict__ wlin,
                          _Float16* __restrict__ whi, _Float16* __restrict__ wlo,
                          const int* __restrict__ flag) {
    int i = blockIdx.x * 256 + threadIdx.x;  // 65536
    float v = (*flag) ? __bfloat162float(((const __hip_bfloat16*)wlin)[i])
                      : ((const float*)wlin)[i];
    _Float16 hi = (_Float16)v;
    whi[i] = hi;
    wlo[i] = (_Float16)(v - (float)hi);
}

// FOFE -> split hi/lo fp16 planes. 256 thr = 2 positions per block.
__global__ void fofe_kernel(const int* __restrict__ chars,
                            const float* __restrict__ fg,
                            unsigned short* __restrict__ xhi,
                            unsigned short* __restrict__ xlo) {
    __shared__ int cS[2][W_];
    int tid = threadIdx.x;
    int sub = tid >> 7;        // 0..1
    int v = tid & 127;
    int bi = blockIdx.x * 2 + sub;  // b*S + s
    if (v < W_) cS[sub][v] = chars[bi * W_ + v];
    __syncthreads();
    float f = fg[0];
    float wt[W_];
    float cur = 1.0f;
#pragma unroll
    for (int w = W_ - 1; w >= 0; --w) {
        bool m = (cS[sub][w] != 0);
        wt[w] = m ? cur : 0.0f;
        if (m) cur *= f;
    }
    float acc = 0.0f;
#pragma unroll
    for (int w = 0; w < W_; ++w) acc += (cS[sub][w] == v) ? wt[w] : 0.0f;
    _Float16 hi = (_Float16)acc;
    _Float16 lo = (_Float16)(acc - (float)hi);
    xhi[(size_t)bi * V_ + v] = f16bits(hi);
    xlo[(size_t)bi * V_ + v] = f16bits(lo);
}

// ---------------------------------------------------------------------------
// Persistent bidirectional GRU.
// R17 = R16's proven tagged exchange + DIRECT-FRAGMENT GATHER (no LDS, no
// per-step barriers).
//   Key fact: the MFMA A-fragment for lane (quad,col) is
//   h[batch=col][k = kk*32+quad*8 .. +7] = 4 contiguous u64s in hbuf per kk.
//   Each thread gathers its own fragments with relaxed agent-scope u64
//   atomic loads (R16-proven transport), validates the per-word tag bit,
//   unpacks hi/lo planes in registers, feeds MFMA directly. The entire LDS
//   redistribution (unpack->ds_write->barrier->ds_read->barrier) is gone.
//   Gather volume rises 4x (per-wave instead of per-block) — all on the
//   MALL-resident 1MB hbuf, bandwidth-trivial.
//   x-fragments load directly from xhi/xlo (plain cached loads, written by
//   fofe_kernel pre-launch; per-batch position sxc computed per thread).
//   x-MFMAs run FIRST, overlapping gather group 0's flight.
//   Gather is chunked: 4 groups x 4 kk x 4 u64; group g+1 issued before
//   group g's MFMAs (software pipeline; later groups arrive pre-validated).
//   Waves fully decouple (no intra-block coupling left); the WAR argument
//   is per-wave via data dependency (R15/R16-proven, unchanged).
// ---------------------------------------------------------------------------
__launch_bounds__(256, 1)
__global__ void gru_kernel(const int* __restrict__ lengths,
                           const _Float16* __restrict__ wh,
                           const float* __restrict__ biasF,
                           const unsigned short* __restrict__ xhi,
                           const unsigned short* __restrict__ xlo,
                           unsigned* __restrict__ hbuf,
                           unsigned* __restrict__ slots,
                           _Float16* __restrict__ Ycat) {
    (void)slots;  // unused
    __shared__ int lenS[16];

    const int tid = threadIdx.x;
    const int chain = blockIdx.x & 15;
    const int blk = blockIdx.x >> 4;    // 0..7
    const int d = chain & 1;
    const int bg = chain >> 1;
    const int b0 = bg * 16;
    const int wave = tid >> 6;          // 0..3
    const int lane = tid & 63;
    const int quad = lane >> 4;
    const int col = lane & 15;
    const int j0w = (blk * 4 + wave) * 16;  // 0..496

    const _Float16* Whh = wh + (d ? 786432 : 0);
    const _Float16* Wih = wh + 1572864 + (d ? 196608 : 0);
    const float* bih = biasF + (d ? 3072 : 0);
    const float* bhh = biasF + 1536 + (d ? 3072 : 0);

    if (tid < 16) lenS[tid] = lengths[b0 + tid];
    __syncthreads();  // init-only barrier

    const int g_r = j0w + col;  // r row; z = 512+g_r; n = 1024+g_r

    // Persistent B fragments: lane holds W[g][kk*32 + quad*8 + 0..7]
    f16x8 br[20], bz[20], bn[20];
#pragma unroll
    for (int kk = 0; kk < 16; ++kk) {
        int k = kk * 32 + quad * 8;
        br[kk] = *(const f16x8*)(Whh + (size_t)(g_r)*H_ + k);
        bz[kk] = *(const f16x8*)(Whh + (size_t)(512 + g_r) * H_ + k);
        bn[kk] = *(const f16x8*)(Whh + (size_t)(1024 + g_r) * H_ + k);
    }
#pragma unroll
    for (int kk = 16; kk < 20; ++kk) {
        int k = (kk - 16) * 32 + quad * 8;
        br[kk] = *(const f16x8*)(Wih + (size_t)(g_r)*V_ + k);
        bz[kk] = *(const f16x8*)(Wih + (size_t)(512 + g_r) * V_ + k);
        bn[kk] = *(const f16x8*)(Wih + (size_t)(1024 + g_r) * V_ + k);
    }

    const float bias_r = bih[g_r] + bhh[g_r];
    const float bias_z = bih[512 + g_r] + bhh[512 + g_r];
    const float bihn = bih[1024 + g_r];
    const float bhhn = bhh[1024 + g_r];

    int len4[4];
#pragma unroll
    for (int i = 0; i < 4; ++i) len4[i] = lenS[quad * 4 + i];
    const int maxlen = lenS[0];   // lengths sorted descending
    const int lenC = lenS[col];   // length of batch 'col' (A-row batch)

    float h_own[4] = {0.f, 0.f, 0.f, 0.f};  // fp32 master state (b=quad*4+i, j=col)

    const unsigned long long tagMsk = (1ULL << 16) | (1ULL << 48);

    for (int t = 0; t < S_; ++t) {
        if (t < maxlen) {
            const int par = t & 1;

            // ---- x fragments: direct plain loads (L2-resident, RO) ----
            const int sxc = d ? max(0, lenC - 1 - t) : t;
            const unsigned short* xrh =
                xhi + ((size_t)(b0 + col) * S_ + sxc) * V_ + quad * 8;
            const unsigned short* xrl =
                xlo + ((size_t)(b0 + col) * S_ + sxc) * V_ + quad * 8;
            int4 xh4[4], xl4[4];
#pragma unroll
            for (int kx = 0; kx < 4; ++kx) {
                xh4[kx] = *(const int4*)(xrh + kx * 32);
                xl4[kx] = *(const int4*)(xrl + kx * 32);
            }

            // ---- h fragment base (u64 units): this thread's A-row = batch col ----
            const unsigned long long* hb =
                (const unsigned long long*)(hbuf +
                    ((size_t)(par * 2 + d) * B_ + b0) * H_) +
                (size_t)col * (H_ / 2) + quad * 4;
            // fragment (kk, j): hb + kk*16 + j   (j = 0..3)

            f32x4 accr = {0.f, 0.f, 0.f, 0.f};
            f32x4 accz = {0.f, 0.f, 0.f, 0.f};
            f32x4 acchn = {0.f, 0.f, 0.f, 0.f};
            f32x4 accxn = {0.f, 0.f, 0.f, 0.f};

            unsigned long long cur[16];
            if (t > 0) {
                // issue gather group 0 (kk 0..3) before x-MFMAs
#pragma unroll
                for (int q = 0; q < 16; ++q)
                    cur[q] = __hip_atomic_load(hb + (size_t)(q >> 2) * 16 + (q & 3),
                                               __ATOMIC_RELAXED, __HIP_MEMORY_SCOPE_AGENT);
            }

            // ---- x-MFMAs first (overlap group-0 flight) ----
#pragma unroll
            for (int kx = 0; kx < 4; ++kx) {
                f16x8 ah = __builtin_bit_cast(f16x8, xh4[kx]);
                f16x8 al = __builtin_bit_cast(f16x8, xl4[kx]);
                accr = __builtin_amdgcn_mfma_f32_16x16x32_f16(ah, br[16 + kx], accr, 0, 0, 0);
                accr = __builtin_amdgcn_mfma_f32_16x16x32_f16(al, br[16 + kx], accr, 0, 0, 0);
                accz = __builtin_amdgcn_mfma_f32_16x16x32_f16(ah, bz[16 + kx], accz, 0, 0, 0);
                accz = __builtin_amdgcn_mfma_f32_16x16x32_f16(al, bz[16 + kx], accz, 0, 0, 0);
                accxn = __builtin_amdgcn_mfma_f32_16x16x32_f16(ah, bn[16 + kx], accxn, 0, 0, 0);
                accxn = __builtin_amdgcn_mfma_f32_16x16x32_f16(al, bn[16 + kx], accxn, 0, 0, 0);
            }

            // ---- h gather + MFMA, 4 pipelined groups of 4 kk ----
            if (t > 0) {
                const unsigned te = ((((unsigned)(t - 1)) >> 1) & 1u) ^ 1u;
                const unsigned long long tagPat =
                    ((unsigned long long)te << 16) | ((unsigned long long)te << 48);
#pragma unroll
                for (int g = 0; g < 4; ++g) {
                    // validate current group (re-load only stale words)
                    unsigned pend = 0xFFFFu;
                    unsigned rounds = 0;
                    while (true) {
                        unsigned np = 0;
#pragma unroll
                        for (int q = 0; q < 16; ++q)
                            if ((pend >> q) & 1u)
                                if ((cur[q] & tagMsk) != tagPat) np |= (1u << q);
                        if (!np) break;
#pragma unroll
                        for (int q = 0; q < 16; ++q)
                            if ((np >> q) & 1u)
                                cur[q] = __hip_atomic_load(
                                    hb + (size_t)(g * 4 + (q >> 2)) * 16 + (q & 3),
                                    __ATOMIC_RELAXED, __HIP_MEMORY_SCOPE_AGENT);
                        pend = np;
                        ++rounds;
                        if (rounds > 4u) __builtin_amdgcn_s_sleep(1);
                        if ((rounds & 31u) == 31u)
                            __builtin_amdgcn_fence(__ATOMIC_ACQUIRE, "agent");
                        if (rounds > 400000u) break;  // malfunction -> visible failure
                    }
                    // issue next group (in flight during this group's MFMAs)
                    unsigned long long nxt[16];
                    if (g < 3) {
#pragma unroll
                        for (int q = 0; q < 16; ++q)
                            nxt[q] = __hip_atomic_load(
                                hb + (size_t)((g + 1) * 4 + (q >> 2)) * 16 + (q & 3),
                                __ATOMIC_RELAXED, __HIP_MEMORY_SCOPE_AGENT);
                    }
                    // unpack + MFMA (kk = g*4 + kk2)
#pragma unroll
                    for (int kk2 = 0; kk2 < 4; ++kk2) {
                        const int kk = g * 4 + kk2;
                        unsigned hi2[4], lo2[4];
#pragma unroll
                        for (int j = 0; j < 4; ++j) {
                            unsigned long long v = cur[kk2 * 4 + j];
                            unsigned p0 = (unsigned)v;
                            unsigned p1 = (unsigned)(v >> 32);
                            hi2[j] = (p0 & 0xffffu) | (p1 << 16);
                            lo2[j] = ((p0 >> 16) | (p1 & 0xffff0000u)) & ~0x00010001u;
                        }
                        int4 h4, l4;
                        h4.x = (int)hi2[0]; h4.y = (int)hi2[1];
                        h4.z = (int)hi2[2]; h4.w = (int)hi2[3];
                        l4.x = (int)lo2[0]; l4.y = (int)lo2[1];
                        l4.z = (int)lo2[2]; l4.w = (int)lo2[3];
                        f16x8 ah = __builtin_bit_cast(f16x8, h4);
                        f16x8 al = __builtin_bit_cast(f16x8, l4);
                        accr = __builtin_amdgcn_mfma_f32_16x16x32_f16(ah, br[kk], accr, 0, 0, 0);
                        accr = __builtin_amdgcn_mfma_f32_16x16x32_f16(al, br[kk], accr, 0, 0, 0);
                        accz = __builtin_amdgcn_mfma_f32_16x16x32_f16(ah, bz[kk], accz, 0, 0, 0);
                        accz = __builtin_amdgcn_mfma_f32_16x16x32_f16(al, bz[kk], accz, 0, 0, 0);
                        acchn = __builtin_amdgcn_mfma_f32_16x16x32_f16(ah, bn[kk], acchn, 0, 0, 0);
                        acchn = __builtin_amdgcn_mfma_f32_16x16x32_f16(al, bn[kk], acchn, 0, 0, 0);
                    }
                    if (g < 3) {
#pragma unroll
                        for (int q = 0; q < 16; ++q) cur[q] = nxt[q];
                    }
                }
            }

            // ---- gates + state update + tagged h stores (fire-and-forget) ----
            unsigned* hwp = hbuf + ((size_t)((1 - par) * 2 + d) * B_ + b0) * H_;
            const unsigned tg = ((((unsigned)t) >> 1) & 1u) ^ 1u;
            float yv[4];
            int so4[4];
#pragma unroll
            for (int i = 0; i < 4; ++i) {
                int bl = quad * 4 + i;
                float r = sigm(accr[i] + bias_r);
                float zg = sigm(accz[i] + bias_z);
                float ng = tanhf_((accxn[i] + bihn) + r * (acchn[i] + bhhn));
                float hcand = (1.0f - zg) * ng + zg * h_own[i];
                bool m = (t < len4[i]);
                yv[i] = m ? hcand : 0.0f;
                h_own[i] = m ? hcand : h_own[i];
                _Float16 hhi = (_Float16)h_own[i];
                _Float16 hlo = (_Float16)(h_own[i] - (float)hhi);
                unsigned packed = (unsigned)f16bits(hhi) |
                                  ((((unsigned)f16bits(hlo) & 0xFFFEu) | tg) << 16);
                __hip_atomic_store(hwp + (size_t)bl * H_ + j0w + col, packed,
                                   __ATOMIC_RELAXED, __HIP_MEMORY_SCOPE_AGENT);
                so4[i] = (d && m) ? (len4[i] - 1 - t) : t;
            }
            // ---- Ycat stores: drain overlaps peers' polling ----
#pragma unroll
            for (int i = 0; i < 4; ++i) {
                int bl = quad * 4 + i;
                Ycat[((size_t)(b0 + bl) * S_ + so4[i]) * 1024 + d * 512 + j0w + col] =
                    (_Float16)yv[i];
            }
        } else {
            // whole group masked: zeros at s_out = t; no exchange traffic
#pragma unroll
            for (int i = 0; i < 4; ++i) {
                int bl = quad * 4 + i;
                Ycat[((size_t)(b0 + bl) * S_ + t) * 1024 + d * 512 + j0w + col] = (_Float16)0.0f;
            }
        }
    }
}

// ---------------------------------------------------------------------------
// Final linear as MFMA GEMM: out[pos,l] = blin[l] + sum_c Y[pos,c]*W[l,c].
// [16384 x 1024] x [1024 x 64]. Block = 256 thr (4 waves), covers 64 pos;
// wave covers 16 pos x 64 l (4 n-tiles). A-frags load directly from Ycat
// (f16x8, layout = verified GRU operand pattern); W as hi/lo f16 planes
// (exact fp32 reconstruction). 256 MFMA/wave; grid 256.
// ---------------------------------------------------------------------------
__launch_bounds__(256, 1)
__global__ void lin_kernel(const _Float16* __restrict__ Ycat,
                           const _Float16* __restrict__ Whi,
                           const _Float16* __restrict__ Wlo,
                           const float* __restrict__ blinF,
                           float* __restrict__ out) {
    const int tid = threadIdx.x;
    const int wave = tid >> 6;
    const int lane = tid & 63;
    const int quad = lane >> 4;
    const int col = lane & 15;
    const int pos0 = blockIdx.x * 64 + wave * 16;

    const _Float16* arow = Ycat + (size_t)(pos0 + col) * 1024 + quad * 8;

    f32x4 acc[4] = {{0.f, 0.f, 0.f, 0.f}, {0.f, 0.f, 0.f, 0.f},
                    {0.f, 0.f, 0.f, 0.f}, {0.f, 0.f, 0.f, 0.f}};
#pragma unroll 4
    for (int c = 0; c < 1024; c += 32) {
        f16x8 a = *(const f16x8*)(arow + c);
#pragma unroll
        for (int nt = 0; nt < 4; ++nt) {
            const size_t wo = (size_t)(nt * 16 + col) * 1024 + c + quad * 8;
            f16x8 bh = *(const f16x8*)(Whi + wo);
            f16x8 bl = *(const f16x8*)(Wlo + wo);
            acc[nt] = __builtin_amdgcn_mfma_f32_16x16x32_f16(a, bh, acc[nt], 0, 0, 0);
            acc[nt] = __builtin_amdgcn_mfma_f32_16x16x32_f16(a, bl, acc[nt], 0, 0, 0);
        }
    }
    // C layout: row = quad*4 + reg (pos), col = lane&15 (l within n-tile)
#pragma unroll
    for (int nt = 0; nt < 4; ++nt) {
        int l = nt * 16 + col;
        float bias = blinF[l];
#pragma unroll
        for (int r = 0; r < 4; ++r) {
            int pos = pos0 + quad * 4 + r;
            out[(size_t)pos * L_ + l] = acc[nt][r] + bias;
        }
    }
}

extern "C" void kernel_launch(void* const* d_in, const int* in_sizes, int n_in,
                              void* d_out, int out_size, void* d_ws, size_t ws_size,
                              hipStream_t stream) {
    const int* chars = (const int*)d_in[0];
    const int* lengths = (const int*)d_in[1];
    const void* forget = d_in[2];
    const void* Wihf = d_in[3];
    const void* Whhf = d_in[4];
    const void* bihf = d_in[5];
    const void* bhhf = d_in[6];
    const void* Wihb = d_in[7];
    const void* Whhb = d_in[8];
    const void* bihb = d_in[9];
    const void* bhhb = d_in[10];
    const void* Wlin = d_in[11];
    const void* blin = d_in[12];
    float* out = (float*)d_out;

    char* ws = (char*)d_ws;
    unsigned* hbuf = (unsigned*)(ws + 0);
    unsigned* slots = (unsigned*)(ws + OFF_SLOT);
    int* flag = (int*)(ws + OFF_FLAG);
    unsigned short* xhi = (unsigned short*)(ws + OFF_XHI);
    unsigned short* xlo = (unsigned short*)(ws + OFF_XLO);
    _Float16* whalf = (_Float16*)(ws + OFF_WH);
    float* smallF = (float*)(ws + OFF_SMALL);
    _Float16* Ycat = (_Float16*)(ws + OFF_YCAT);
    _Float16* wlh = (_Float16*)(ws + OFF_WLH);
    _Float16* wll = (_Float16*)(ws + OFF_WLL);

    // zero h state (both parities, tag bits = 0) + slots + flag
    (void)hipMemsetAsync(ws, 0, OFF_XHI, stream);

    hipLaunchKernelGGL(detect_kernel, dim3(1), dim3(256), 0, stream,
                       (const unsigned*)Whhf, flag);
    hipLaunchKernelGGL(prep_whalf, dim3(1966080 / 256), dim3(256), 0, stream,
                       Whhf, Whhb, Wihf, Wihb, whalf, flag);
    hipLaunchKernelGGL(prep_small, dim3(281), dim3(256), 0, stream,
                       bihf, bhhf, bihb, bhhb, Wlin, blin, forget, smallF, flag);
    hipLaunchKernelGGL(prep_wlin, dim3(256), dim3(256), 0, stream,
                       Wlin, wlh, wll, flag);
    hipLaunchKernelGGL(fofe_kernel, dim3(B_ * S_ / 2), dim3(256), 0, stream,
                       chars, smallF + 71744, xhi, xlo);

    // 16 chains x 8 blocks x 256 threads; direct-fragment tagged exchange.
    hipLaunchKernelGGL(gru_kernel, dim3(128), dim3(256), 0, stream,
                       lengths, whalf, smallF, xhi, xlo, hbuf, slots, Ycat);

    // MFMA GEMM epilogue: 256 blocks x 64 pos.
    hipLaunchKernelGGL(lin_kernel, dim3(256), dim3(256), 0, stream,
                       Ycat, wlh, wll, smallF + 71680, out);
}

// Round 9
// 591.271 us; speedup vs baseline: 2.3790x; 2.3790x over previous
//
#include <hip/hip_runtime.h>
#include <hip/hip_bf16.h>

// Problem constants
#define B_ 128
#define S_ 128
#define W_ 16
#define V_ 128
#define H_ 512
#define L_ 64

typedef _Float16 f16x8 __attribute__((ext_vector_type(8)));
typedef float f32x4 __attribute__((ext_vector_type(4)));

__device__ __forceinline__ float sigm(float v) { return 1.0f / (1.0f + __expf(-v)); }
__device__ __forceinline__ float tanhf_(float v) { return 1.0f - 2.0f / (1.0f + __expf(2.0f * v)); }

__device__ __forceinline__ unsigned short f16bits(_Float16 h) {
    return __builtin_bit_cast(unsigned short, h);
}

// ---------------------------------------------------------------------------
// Workspace layout (bytes):
//   hbuf  u32 packed(hi,lo) [par2][dir2][128][512] @ 0        (1048576)
//   slots u32 [16 chains][8 blocks][32 pad]        @ 1048576  (16384)  (unused)
//   flag  i32                                      @ 1064960  (64)
//   xhi   u16 [128][128][128]                      @ 1065024  (4194304)
//   xlo   u16 [128][128][128]                      @ 5259328  (4194304)
//   whalf f16 [1966080]                            @ 9453632  (3932160)
//         [whhf 786432 | whhb 786432 | wihf 196608 | wihb 196608]
//   smallF f32 [71745]                             @ 13385792 (287040)
//         [bihf 1536|bhhf 1536|bihb 1536|bhhb 1536|wlin 65536|blin 64|fg 1]
//   Ycat  f16 [128][128][1024]                     @ 13672832 (33554432)
//   wlinh f16 [64][1024]                           @ 47227264 (131072)
//   wlinl f16 [64][1024]                           @ 47358336 (131072) -> ends 47489408
// ---------------------------------------------------------------------------
#define OFF_SLOT  1048576
#define OFF_FLAG  1064960
#define OFF_XHI   1065024
#define OFF_XLO   5259328
#define OFF_WH    9453632
#define OFF_SMALL 13385792
#define OFF_YCAT  13672832
#define OFF_WLH   47227264
#define OFF_WLL   47358336

// Runtime input-dtype detection (insurance): low-16 exponent-field vote.
__global__ void detect_kernel(const unsigned* __restrict__ w, int* __restrict__ flag) {
    __shared__ int sv[256];
    int tid = threadIdx.x;
    unsigned word = w[tid];
    unsigned e = (word >> 7) & 0xFFu;
    sv[tid] = (e >= 64u && e <= 126u) ? 1 : 0;
    __syncthreads();
    for (int s = 128; s > 0; s >>= 1) {
        if (tid < s) sv[tid] += sv[tid + s];
        __syncthreads();
    }
    if (tid == 0) *flag = (sv[0] >= 160) ? 1 : 0;  // 1 = inputs are bf16
}

// ---------------------------------------------------------------------------
// R18: ALL prep work fused into one dispatch (3 launch gaps saved).
//   bid <  7680           : whalf canonicalization (fp16 RTN)
//   bid <  7961           : biases/W_lin/b_lin/forget -> fp32
//   bid <  8217           : W_lin hi/lo f16 planes
//   else (8192 blocks)    : FOFE -> xhi/xlo (reads forget from raw input)
// ---------------------------------------------------------------------------
__global__ void prep_all(const void* __restrict__ whhf, const void* __restrict__ whhb,
                         const void* __restrict__ wihf, const void* __restrict__ wihb,
                         const void* __restrict__ bihf, const void* __restrict__ bhhf,
                         const void* __restrict__ bihb, const void* __restrict__ bhhb,
                         const void* __restrict__ wlin, const void* __restrict__ blin,
                         const void* __restrict__ fgp, const int* __restrict__ chars,
                         _Float16* __restrict__ whalf, float* __restrict__ smallF,
                         _Float16* __restrict__ whi, _Float16* __restrict__ wlo,
                         unsigned short* __restrict__ xhi, unsigned short* __restrict__ xlo,
                         const int* __restrict__ flag) {
    const int bid = blockIdx.x;
    const int tid = threadIdx.x;
    const int fl = *flag;
    if (bid < 7680) {
        int i = bid * 256 + tid;  // 1966080 exactly
        const void* src;
        int off;
        if (i < 786432)       { src = whhf; off = i; }
        else if (i < 1572864) { src = whhb; off = i - 786432; }
        else if (i < 1769472) { src = wihf; off = i - 1572864; }
        else                  { src = wihb; off = i - 1769472; }
        float v = fl ? __bfloat162float(((const __hip_bfloat16*)src)[off])
                     : ((const float*)src)[off];
        whalf[i] = (_Float16)v;
    } else if (bid < 7961) {
        int i = (bid - 7680) * 256 + tid;
        if (i >= 71745) return;
        const void* src;
        int off;
        if (i < 1536)       { src = bihf; off = i; }
        else if (i < 3072)  { src = bhhf; off = i - 1536; }
        else if (i < 4608)  { src = bihb; off = i - 3072; }
        else if (i < 6144)  { src = bhhb; off = i - 4608; }
        else if (i < 71680) { src = wlin; off = i - 6144; }
        else if (i < 71744) { src = blin; off = i - 71680; }
        else                { src = fgp;  off = 0; }
        float v = fl ? __bfloat162float(((const __hip_bfloat16*)src)[off])
                     : ((const float*)src)[off];
        smallF[i] = v;
    } else if (bid < 8217) {
        int i = (bid - 7961) * 256 + tid;  // 65536
        float v = fl ? __bfloat162float(((const __hip_bfloat16*)wlin)[i])
                     : ((const float*)wlin)[i];
        _Float16 hi = (_Float16)v;
        whi[i] = hi;
        wlo[i] = (_Float16)(v - (float)hi);
    } else {
        // FOFE: 2 positions per block
        __shared__ int cS[2][W_];
        const int fb = bid - 8217;
        int sub = tid >> 7;
        int v = tid & 127;
        int bi = fb * 2 + sub;  // b*S + s
        if (v < W_) cS[sub][v] = chars[bi * W_ + v];
        __syncthreads();
        float f = fl ? __bfloat162float(*(const __hip_bfloat16*)fgp)
                     : *(const float*)fgp;
        float wt[W_];
        float cur = 1.0f;
#pragma unroll
        for (int w = W_ - 1; w >= 0; --w) {
            bool m = (cS[sub][w] != 0);
            wt[w] = m ? cur : 0.0f;
            if (m) cur *= f;
        }
        float acc = 0.0f;
#pragma unroll
        for (int w = 0; w < W_; ++w) acc += (cS[sub][w] == v) ? wt[w] : 0.0f;
        _Float16 hi = (_Float16)acc;
        _Float16 lo = (_Float16)(acc - (float)hi);
        xhi[(size_t)bi * V_ + v] = f16bits(hi);
        xlo[(size_t)bi * V_ + v] = f16bits(lo);
    }
}

// ---------------------------------------------------------------------------
// Persistent bidirectional GRU.
// R18 = R16 champion (494us gru: tagged fire-and-forget exchange, relaxed
// agent atomics, block-cooperative LDS transpose) + LDS DOUBLE-BUFFER so
// barrier B is removed.
//   WAR proof for single-barrier double-buffer: buffer[par] written at t is
//   next overwritten at t+2. Any wave W stages t+2 only after passing
//   barrier A of t+1; every wave X at barrier A of t+1 has (program order)
//   finished reads(t) -> stores(t) -> volley(t+1) -> stage(t+1). So all
//   reads of buffer[par]@t are complete before any t+2 overwrite. Barrier A
//   (post-staging RAW gate) remains — it is the only barrier per step.
// R17's direct-fragment gather REVERTED: measured 2.6x regression (4x MALL
// traffic + group-serialized stalls).
// ---------------------------------------------------------------------------
__launch_bounds__(256, 1)
__global__ void gru_kernel(const int* __restrict__ lengths,
                           const _Float16* __restrict__ wh,
                           const float* __restrict__ biasF,
                           const unsigned short* __restrict__ xhi,
                           const unsigned short* __restrict__ xlo,
                           unsigned* __restrict__ hbuf,
                           unsigned* __restrict__ slots,
                           _Float16* __restrict__ Ycat) {
    (void)slots;  // unused
    constexpr int RSTR = 656;  // 640 + 16 pad halves (0 conflicts measured r5/r7)
    __shared__ _Float16 Ahi[2][16 * RSTR];
    __shared__ _Float16 Alo[2][16 * RSTR];
    __shared__ int lenS[16];

    const int tid = threadIdx.x;
    const int chain = blockIdx.x & 15;
    const int blk = blockIdx.x >> 4;    // 0..7
    const int d = chain & 1;
    const int bg = chain >> 1;
    const int b0 = bg * 16;
    const int wave = tid >> 6;          // 0..3
    const int lane = tid & 63;
    const int quad = lane >> 4;
    const int col = lane & 15;
    const int j0w = (blk * 4 + wave) * 16;  // 0..496

    const _Float16* Whh = wh + (d ? 786432 : 0);
    const _Float16* Wih = wh + 1572864 + (d ? 196608 : 0);
    const float* bih = biasF + (d ? 3072 : 0);
    const float* bhh = biasF + 1536 + (d ? 3072 : 0);

    if (tid < 16) lenS[tid] = lengths[b0 + tid];
    __syncthreads();

    const int g_r = j0w + col;  // r row; z = 512+g_r; n = 1024+g_r

    // Persistent B fragments: lane holds W[g][kk*32 + quad*8 + 0..7]
    f16x8 br[20], bz[20], bn[20];
#pragma unroll
    for (int kk = 0; kk < 16; ++kk) {
        int k = kk * 32 + quad * 8;
        br[kk] = *(const f16x8*)(Whh + (size_t)(g_r)*H_ + k);
        bz[kk] = *(const f16x8*)(Whh + (size_t)(512 + g_r) * H_ + k);
        bn[kk] = *(const f16x8*)(Whh + (size_t)(1024 + g_r) * H_ + k);
    }
#pragma unroll
    for (int kk = 16; kk < 20; ++kk) {
        int k = (kk - 16) * 32 + quad * 8;
        br[kk] = *(const f16x8*)(Wih + (size_t)(g_r)*V_ + k);
        bz[kk] = *(const f16x8*)(Wih + (size_t)(512 + g_r) * V_ + k);
        bn[kk] = *(const f16x8*)(Wih + (size_t)(1024 + g_r) * V_ + k);
    }

    const float bias_r = bih[g_r] + bhh[g_r];
    const float bias_z = bih[512 + g_r] + bhh[512 + g_r];
    const float bihn = bih[1024 + g_r];
    const float bhhn = bhh[1024 + g_r];

    int len4[4];
#pragma unroll
    for (int i = 0; i < 4; ++i) len4[i] = lenS[quad * 4 + i];
    const int maxlen = lenS[0];  // lengths sorted descending

    float h_own[4] = {0.f, 0.f, 0.f, 0.f};  // fp32 master state (b=quad*4+i, j=col)

    // x staging: 16 rows x 16 chunks of 8 halves (int4 per plane per thread)
    const int xb = tid >> 4;
    const int xv8 = (tid & 15) * 8;

    const unsigned long long tagMsk = (1ULL << 16) | (1ULL << 48);

    for (int t = 0; t < S_; ++t) {
        if (t < maxlen) {
            const int par = t & 1;
            const _Float16* arh = &Ahi[par][col * RSTR + quad * 8];
            const _Float16* arl = &Alo[par][col * RSTR + quad * 8];
            // ---- x loads (plain cached, RO; issued first, overlap volley) ----
            int lxb = lenS[xb];
            int sxb = d ? max(0, lxb - 1 - t) : t;
            int4 xh4 = *(const int4*)(xhi + ((size_t)(b0 + xb) * S_ + sxb) * V_ + xv8);
            int4 xl4 = *(const int4*)(xlo + ((size_t)(b0 + xb) * S_ + sxb) * V_ + xv8);

            // ---- h gather: tag-validated volley of relaxed agent u64 loads.
            //      Row i = batch i, col-pair (2*tid, 2*tid+1). ----
            unsigned* hrp = hbuf + ((size_t)(par * 2 + d) * B_ + b0) * H_;
            unsigned long long hv[16];
            if (t > 0) {
                const unsigned te = ((((unsigned)(t - 1)) >> 1) & 1u) ^ 1u;
                const unsigned long long tagPat =
                    ((unsigned long long)te << 16) | ((unsigned long long)te << 48);
                unsigned pend = 0xFFFFu;
                unsigned round = 0;
                while (true) {
#pragma unroll
                    for (int i = 0; i < 16; ++i)
                        if (pend & (1u << i))
                            hv[i] = __hip_atomic_load(
                                (const unsigned long long*)(hrp + (size_t)i * H_ + tid * 2),
                                __ATOMIC_RELAXED, __HIP_MEMORY_SCOPE_AGENT);
                    unsigned np = 0;
#pragma unroll
                    for (int i = 0; i < 16; ++i)
                        if ((pend & (1u << i)) && (hv[i] & tagMsk) != tagPat) np |= (1u << i);
                    pend = np;
                    if (!pend) break;
                    ++round;
                    if (round > 4u) __builtin_amdgcn_s_sleep(1);
                    if ((round & 31u) == 31u)  // stale-L2 insurance; free if unused
                        __builtin_amdgcn_fence(__ATOMIC_ACQUIRE, "agent");
                    if (round > 400000u) break;  // malfunction -> visible failure
                }
            } else {
                // t=0: initial h is all zeros (memset) — no loads needed
#pragma unroll
                for (int i = 0; i < 16; ++i) hv[i] = 0ULL;
            }

            // ---- stage x into LDS[par] ----
            *(int4*)&Ahi[par][xb * RSTR + 512 + xv8] = xh4;
            *(int4*)&Alo[par][xb * RSTR + 512 + xv8] = xl4;
            // ---- unpack h (clear tag bits) and stage into LDS[par] ----
#pragma unroll
            for (int i = 0; i < 16; ++i) {
                unsigned p0 = (unsigned)hv[i];
                unsigned p1 = (unsigned)(hv[i] >> 32);
                unsigned hi2 = (p0 & 0xffffu) | (p1 << 16);
                unsigned lo2 = ((p0 >> 16) | (p1 & 0xffff0000u)) & ~0x00010001u;
                *(unsigned*)&Ahi[par][i * RSTR + tid * 2] = hi2;
                *(unsigned*)&Alo[par][i * RSTR + tid * 2] = lo2;
            }
            __syncthreads();  // A: staging complete (only barrier per step)

            // ---- MFMA: hw = (h_hi + h_lo) @ W^T (fp16 in, fp32 acc) ----
            f32x4 accr = {0.f, 0.f, 0.f, 0.f};
            f32x4 accz = {0.f, 0.f, 0.f, 0.f};
            f32x4 acchn = {0.f, 0.f, 0.f, 0.f};
            f32x4 accxn = {0.f, 0.f, 0.f, 0.f};
#pragma unroll
            for (int kk = 0; kk < 16; ++kk) {
                f16x8 ah = *(const f16x8*)(arh + kk * 32);
                f16x8 al = *(const f16x8*)(arl + kk * 32);
                accr = __builtin_amdgcn_mfma_f32_16x16x32_f16(ah, br[kk], accr, 0, 0, 0);
                accr = __builtin_amdgcn_mfma_f32_16x16x32_f16(al, br[kk], accr, 0, 0, 0);
                accz = __builtin_amdgcn_mfma_f32_16x16x32_f16(ah, bz[kk], accz, 0, 0, 0);
                accz = __builtin_amdgcn_mfma_f32_16x16x32_f16(al, bz[kk], accz, 0, 0, 0);
                acchn = __builtin_amdgcn_mfma_f32_16x16x32_f16(ah, bn[kk], acchn, 0, 0, 0);
                acchn = __builtin_amdgcn_mfma_f32_16x16x32_f16(al, bn[kk], acchn, 0, 0, 0);
            }
#pragma unroll
            for (int kk = 16; kk < 20; ++kk) {
                f16x8 ah = *(const f16x8*)(arh + 512 + (kk - 16) * 32);
                f16x8 al = *(const f16x8*)(arl + 512 + (kk - 16) * 32);
                accr = __builtin_amdgcn_mfma_f32_16x16x32_f16(ah, br[kk], accr, 0, 0, 0);
                accr = __builtin_amdgcn_mfma_f32_16x16x32_f16(al, br[kk], accr, 0, 0, 0);
                accz = __builtin_amdgcn_mfma_f32_16x16x32_f16(ah, bz[kk], accz, 0, 0, 0);
                accz = __builtin_amdgcn_mfma_f32_16x16x32_f16(al, bz[kk], accz, 0, 0, 0);
                accxn = __builtin_amdgcn_mfma_f32_16x16x32_f16(ah, bn[kk], accxn, 0, 0, 0);
                accxn = __builtin_amdgcn_mfma_f32_16x16x32_f16(al, bn[kk], accxn, 0, 0, 0);
            }
            // (barrier B removed — WAR covered by barrier A of t+1, see header)

            // ---- gates + state update + tagged h stores (fire-and-forget) ----
            unsigned* hwp = hbuf + ((size_t)((1 - par) * 2 + d) * B_ + b0) * H_;
            const unsigned tg = ((((unsigned)t) >> 1) & 1u) ^ 1u;
            float yv[4];
            int so4[4];
#pragma unroll
            for (int i = 0; i < 4; ++i) {
                int bl = quad * 4 + i;
                float r = sigm(accr[i] + bias_r);
                float zg = sigm(accz[i] + bias_z);
                float ng = tanhf_((accxn[i] + bihn) + r * (acchn[i] + bhhn));
                float hcand = (1.0f - zg) * ng + zg * h_own[i];
                bool m = (t < len4[i]);
                yv[i] = m ? hcand : 0.0f;
                h_own[i] = m ? hcand : h_own[i];
                _Float16 hhi = (_Float16)h_own[i];
                _Float16 hlo = (_Float16)(h_own[i] - (float)hhi);
                unsigned packed = (unsigned)f16bits(hhi) |
                                  ((((unsigned)f16bits(hlo) & 0xFFFEu) | tg) << 16);
                __hip_atomic_store(hwp + (size_t)bl * H_ + j0w + col, packed,
                                   __ATOMIC_RELAXED, __HIP_MEMORY_SCOPE_AGENT);
                so4[i] = (d && m) ? (len4[i] - 1 - t) : t;
            }
            // ---- Ycat stores: drain overlaps peers' polling ----
#pragma unroll
            for (int i = 0; i < 4; ++i) {
                int bl = quad * 4 + i;
                Ycat[((size_t)(b0 + bl) * S_ + so4[i]) * 1024 + d * 512 + j0w + col] =
                    (_Float16)yv[i];
            }
        } else {
            // whole group masked: zeros at s_out = t; no exchange traffic
#pragma unroll
            for (int i = 0; i < 4; ++i) {
                int bl = quad * 4 + i;
                Ycat[((size_t)(b0 + bl) * S_ + t) * 1024 + d * 512 + j0w + col] = (_Float16)0.0f;
            }
        }
    }
}

// ---------------------------------------------------------------------------
// Final linear as MFMA GEMM: out[pos,l] = blin[l] + sum_c Y[pos,c]*W[l,c].
// [16384 x 1024] x [1024 x 64]. Block = 256 thr (4 waves), covers 64 pos;
// wave covers 16 pos x 64 l (4 n-tiles). A-frags load directly from Ycat
// (f16x8, layout = verified GRU operand pattern); W as hi/lo f16 planes
// (exact fp32 reconstruction). 256 MFMA/wave; grid 256.
// ---------------------------------------------------------------------------
__launch_bounds__(256, 1)
__global__ void lin_kernel(const _Float16* __restrict__ Ycat,
                           const _Float16* __restrict__ Whi,
                           const _Float16* __restrict__ Wlo,
                           const float* __restrict__ blinF,
                           float* __restrict__ out) {
    const int tid = threadIdx.x;
    const int wave = tid >> 6;
    const int lane = tid & 63;
    const int quad = lane >> 4;
    const int col = lane & 15;
    const int pos0 = blockIdx.x * 64 + wave * 16;

    const _Float16* arow = Ycat + (size_t)(pos0 + col) * 1024 + quad * 8;

    f32x4 acc[4] = {{0.f, 0.f, 0.f, 0.f}, {0.f, 0.f, 0.f, 0.f},
                    {0.f, 0.f, 0.f, 0.f}, {0.f, 0.f, 0.f, 0.f}};
#pragma unroll 4
    for (int c = 0; c < 1024; c += 32) {
        f16x8 a = *(const f16x8*)(arow + c);
#pragma unroll
        for (int nt = 0; nt < 4; ++nt) {
            const size_t wo = (size_t)(nt * 16 + col) * 1024 + c + quad * 8;
            f16x8 bh = *(const f16x8*)(Whi + wo);
            f16x8 bl = *(const f16x8*)(Wlo + wo);
            acc[nt] = __builtin_amdgcn_mfma_f32_16x16x32_f16(a, bh, acc[nt], 0, 0, 0);
            acc[nt] = __builtin_amdgcn_mfma_f32_16x16x32_f16(a, bl, acc[nt], 0, 0, 0);
        }
    }
    // C layout: row = quad*4 + reg (pos), col = lane&15 (l within n-tile)
#pragma unroll
    for (int nt = 0; nt < 4; ++nt) {
        int l = nt * 16 + col;
        float bias = blinF[l];
#pragma unroll
        for (int r = 0; r < 4; ++r) {
            int pos = pos0 + quad * 4 + r;
            out[(size_t)pos * L_ + l] = acc[nt][r] + bias;
        }
    }
}

extern "C" void kernel_launch(void* const* d_in, const int* in_sizes, int n_in,
                              void* d_out, int out_size, void* d_ws, size_t ws_size,
                              hipStream_t stream) {
    const int* chars = (const int*)d_in[0];
    const int* lengths = (const int*)d_in[1];
    const void* forget = d_in[2];
    const void* Wihf = d_in[3];
    const void* Whhf = d_in[4];
    const void* bihf = d_in[5];
    const void* bhhf = d_in[6];
    const void* Wihb = d_in[7];
    const void* Whhb = d_in[8];
    const void* bihb = d_in[9];
    const void* bhhb = d_in[10];
    const void* Wlin = d_in[11];
    const void* blin = d_in[12];
    float* out = (float*)d_out;

    char* ws = (char*)d_ws;
    unsigned* hbuf = (unsigned*)(ws + 0);
    unsigned* slots = (unsigned*)(ws + OFF_SLOT);
    int* flag = (int*)(ws + OFF_FLAG);
    unsigned short* xhi = (unsigned short*)(ws + OFF_XHI);
    unsigned short* xlo = (unsigned short*)(ws + OFF_XLO);
    _Float16* whalf = (_Float16*)(ws + OFF_WH);
    float* smallF = (float*)(ws + OFF_SMALL);
    _Float16* Ycat = (_Float16*)(ws + OFF_YCAT);
    _Float16* wlh = (_Float16*)(ws + OFF_WLH);
    _Float16* wll = (_Float16*)(ws + OFF_WLL);

    // zero h state (both parities, tag bits = 0) + slots + flag
    (void)hipMemsetAsync(ws, 0, OFF_XHI, stream);

    hipLaunchKernelGGL(detect_kernel, dim3(1), dim3(256), 0, stream,
                       (const unsigned*)Whhf, flag);
    // fused prep: whalf (7680) + small (281) + wlin planes (256) + fofe (8192)
    hipLaunchKernelGGL(prep_all, dim3(16409), dim3(256), 0, stream,
                       Whhf, Whhb, Wihf, Wihb, bihf, bhhf, bihb, bhhb,
                       Wlin, blin, forget, chars,
                       whalf, smallF, wlh, wll, xhi, xlo, flag);

    // 16 chains x 8 blocks x 256 threads; tagged fire-and-forget exchange.
    hipLaunchKernelGGL(gru_kernel, dim3(128), dim3(256), 0, stream,
                       lengths, whalf, smallF, xhi, xlo, hbuf, slots, Ycat);

    // MFMA GEMM epilogue: 256 blocks x 64 pos.
    hipLaunchKernelGGL(lin_kernel, dim3(256), dim3(256), 0, stream,
                       Ycat, wlh, wll, smallF + 71680, out);
}